// Round 8
// baseline (5836.692 us; speedup 1.0000x reference)
//
#include <hip/hip_runtime.h>

typedef unsigned short ushort_t;
typedef unsigned int uint_t;
typedef __attribute__((ext_vector_type(8))) short bf16x8;
typedef __attribute__((ext_vector_type(4))) float f32x4;
typedef __attribute__((ext_vector_type(4))) unsigned int uintx4;

#define B_  16
#define S_  1024
#define D_  1024
#define U_  512
#define GU_ 1536  // 3*U

// ---------- bf16 helpers (RNE) ----------
__device__ __forceinline__ ushort_t f2bf(float f) {
  union { float f; uint_t u; } v; v.f = f;
  uint_t r = v.u + 0x7fffu + ((v.u >> 16) & 1u);
  return (ushort_t)(r >> 16);
}
__device__ __forceinline__ float bf2f(ushort_t b) {
  union { uint_t u; float f; } v; v.u = ((uint_t)b) << 16; return v.f;
}

// row permute for [b*S+s] -> [s*16+b] layouts (M=16384, S=1024, B=16)
__device__ __forceinline__ int rp16(int m) {
  return ((m & 1023) << 4) | (m >> 10);
}

// ---------- fp32 -> bf16 weight conversion ----------
__global__ void cvt_f32_bf16(const float4* __restrict__ in, ushort4* __restrict__ out, int n4) {
  int i = blockIdx.x * blockDim.x + threadIdx.x;
  int stride = gridDim.x * blockDim.x;
  for (; i < n4; i += stride) {
    float4 f = in[i];
    ushort4 o; o.x = f2bf(f.x); o.y = f2bf(f.y); o.z = f2bf(f.z); o.w = f2bf(f.w);
    out[i] = o;
  }
}

// ---------- LayerNorm: x fp32 [BS, 1024] -> xn bf16 ----------
__global__ __launch_bounds__(256) void ln_kernel(
    const float* __restrict__ x, const float* __restrict__ gamma,
    const float* __restrict__ beta, ushort_t* __restrict__ xn)
{
  int row = blockIdx.x;
  int t = threadIdx.x;
  const float* xr = x + (size_t)row * 1024;
  float4 v = *(const float4*)(xr + t * 4);
  float s = v.x + v.y + v.z + v.w;
  float ss = v.x * v.x + v.y * v.y + v.z * v.z + v.w * v.w;
#pragma unroll
  for (int o = 32; o > 0; o >>= 1) {
    s  += __shfl_down(s, o, 64);
    ss += __shfl_down(ss, o, 64);
  }
  __shared__ float red[2][4];
  __shared__ float mv[2];
  int wv = t >> 6, ln = t & 63;
  if (ln == 0) { red[0][wv] = s; red[1][wv] = ss; }
  __syncthreads();
  if (t == 0) {
    float S1 = red[0][0] + red[0][1] + red[0][2] + red[0][3];
    float S2 = red[1][0] + red[1][1] + red[1][2] + red[1][3];
    float mu = S1 * (1.f / 1024.f);
    float var = S2 * (1.f / 1024.f) - mu * mu;
    mv[0] = mu;
    mv[1] = rsqrtf(var + 1e-5f);
  }
  __syncthreads();
  float mu = mv[0], rs = mv[1];
  float4 gm = *(const float4*)(gamma + t * 4);
  float4 bt = *(const float4*)(beta + t * 4);
  ushort4 o;
  o.x = f2bf((v.x - mu) * rs * gm.x + bt.x);
  o.y = f2bf((v.y - mu) * rs * gm.y + bt.y);
  o.z = f2bf((v.z - mu) * rs * gm.z + bt.z);
  o.w = f2bf((v.w - mu) * rs * gm.w + bt.w);
  *(ushort4*)(xn + (size_t)row * 1024 + t * 4) = o;
}

// ---------- GEMM: C[M,N] = A[M,K](bf16) @ Bw[N,K](bf16)^T + bias (+resid) ----
template<int RES, int OBF, int APERM, int CPERM>
__global__ __launch_bounds__(256, 2) void gemm_bt(
    const ushort_t* __restrict__ A, const ushort_t* __restrict__ Bw,
    const float* __restrict__ bias, const float* __restrict__ resid,
    void* __restrict__ Cout, int M, int N, int K)
{
  __shared__ ushort_t As[128][40];
  __shared__ ushort_t Bs[128][40];
  int bm = blockIdx.x, bn = blockIdx.y;
  int tid = threadIdx.x;
  int wave = tid >> 6, lane = tid & 63;
  int wm = wave >> 1, wn = wave & 1;
  int q = lane >> 4, l16 = lane & 15;
  f32x4 acc[4][4];
#pragma unroll
  for (int i = 0; i < 4; i++)
#pragma unroll
    for (int j = 0; j < 4; j++) acc[i][j] = (f32x4){0.f, 0.f, 0.f, 0.f};
  int r0 = tid >> 2, kc = tid & 3;
  const int nk = K >> 5;
  for (int it = 0; it < nk; ++it) {
#pragma unroll
    for (int h = 0; h < 2; ++h) {
      int r = r0 + h * 64;
      int arow = bm * 128 + r;
      if (APERM) arow = rp16(arow);
      const uint4* pa = (const uint4*)(A + (size_t)arow * K + it * 32 + kc * 8);
      *(uint4*)&As[r][kc * 8] = *pa;
      const uint4* pb = (const uint4*)(Bw + (size_t)(bn * 128 + r) * K + it * 32 + kc * 8);
      *(uint4*)&Bs[r][kc * 8] = *pb;
    }
    __syncthreads();
    bf16x8 af[4], bfr[4];
#pragma unroll
    for (int i = 0; i < 4; i++) af[i]  = *(bf16x8*)&As[wm * 64 + i * 16 + l16][q * 8];
#pragma unroll
    for (int j = 0; j < 4; j++) bfr[j] = *(bf16x8*)&Bs[wn * 64 + j * 16 + l16][q * 8];
#pragma unroll
    for (int i = 0; i < 4; i++)
#pragma unroll
      for (int j = 0; j < 4; j++)
        acc[i][j] = __builtin_amdgcn_mfma_f32_16x16x32_bf16(af[i], bfr[j], acc[i][j], 0, 0, 0);
    __syncthreads();
  }
#pragma unroll
  for (int i = 0; i < 4; i++) {
#pragma unroll
    for (int j = 0; j < 4; j++) {
      int n = bn * 128 + wn * 64 + j * 16 + l16;
      float bv = bias[n];
#pragma unroll
      for (int rr = 0; rr < 4; rr++) {
        int m = bm * 128 + wm * 64 + i * 16 + q * 4 + rr;
        float v = acc[i][j][rr] + bv;
        if (RES) v += resid[(size_t)m * N + n];
        int cm = CPERM ? rp16(m) : m;
        if (OBF) ((ushort_t*)Cout)[(size_t)cm * N + n] = f2bf(v);
        else     ((float*)Cout)[(size_t)cm * N + n] = v;
      }
    }
  }
}

// ======================================================================
// GRU scan v8 = v7 (speculative self-validating mailbox, parallel retry
// rounds — PASSED correctness in R6) with the spill removed: ALL w_hh
// fragments live in LDS (96 KB, v2/v5's proven layout), freeing the 96
// wreg VGPRs so the in-flight slice buffer sv[16][2] (128 VGPRs) fits in
// registers. R6's regression was scratch traffic (VGPR_Count 160 vs ~270
// live => spill; FETCH +119MB), not the protocol.
//   Mailbox dword = (step+1)<<16 | bf16(h); tag travels inside the
//   payload (dword writeback atomic) -> publish is 4 fire-and-forget
//   sc0 sc1 stores, no drain/tag-line/poll/barrier. Consumer issues all
//   16 slice reads at the TAIL (right after publishing); at the next
//   head: one vmcnt(0) + sched_barrier(0), validate all 16 slices,
//   reissue ONLY stale slices in one parallel batch per retry round.
// Slot safety: 2-slot ping-pong with v2's induction (a wg overwrites
// slot p at step s+2 only after validating ALL of h(s+1), which required
// every wg to have published h(s+1), i.e. finished reading h(s); its own
// in-flight reads were drained by its head vmcnt(0) before publishing).
// Stale/mixed snapshots always carry tag != want. Bounded budget ->
// falsified assumption = slow clean FAIL, never a hang.
// ======================================================================

__device__ __forceinline__ uint_t vbad(const uintx4& a, const uintx4& b, uint_t wantw) {
  uint_t t0 = __builtin_amdgcn_perm(a[1], a[0], 0x07060302u);
  uint_t t1 = __builtin_amdgcn_perm(a[3], a[2], 0x07060302u);
  uint_t t2 = __builtin_amdgcn_perm(b[1], b[0], 0x07060302u);
  uint_t t3 = __builtin_amdgcn_perm(b[3], b[2], 0x07060302u);
  return (t0 ^ wantw) | (t1 ^ wantw) | (t2 ^ wantw) | (t3 ^ wantw);
}

__global__ __launch_bounds__(128, 1) void scan_kernel(
    const ushort_t* __restrict__ gx, const float* __restrict__ w_hh,
    const float* __restrict__ b_hh, uint_t* __restrict__ mdata,
    ushort_t* __restrict__ y, float* __restrict__ h_last)
{
  extern __shared__ char smem[];
  ushort_t* wlds = (ushort_t*)smem;   // 96 KB: [gi*2+wv][ks 0..15][lane*8] B-frags

  const int m = blockIdx.x;
  const int c0 = m * 32;
  const int t = threadIdx.x;
  const int wv = t >> 6, lane = t & 63, q = lane >> 4, l16 = lane & 15;
  const int cl = (wv << 4) + l16;      // owned hcol within slice, 0..31

  // ---- ALL w_hh fragments (ks 0..15, both wave col-halves) into LDS ----
  for (int idx = t; idx < 96 * 64; idx += 128) {
    int cc = idx >> 6, ln = idx & 63;
    int gi = cc >> 5, wv2 = (cc >> 4) & 1, ks = cc & 15;
    int n = c0 + (wv2 << 4) + (ln & 15);
    int k0 = (ks << 5) + ((ln >> 4) << 3);
    const float* src = w_hh + (size_t)(gi * 512 + n) * 512 + k0;
    float4 f0 = *(const float4*)src;
    float4 f1 = *(const float4*)(src + 4);
    uint4 pk;
    pk.x = (uint_t)f2bf(f0.x) | ((uint_t)f2bf(f0.y) << 16);
    pk.y = (uint_t)f2bf(f0.z) | ((uint_t)f2bf(f0.w) << 16);
    pk.z = (uint_t)f2bf(f1.x) | ((uint_t)f2bf(f1.y) << 16);
    pk.w = (uint_t)f2bf(f1.z) | ((uint_t)f2bf(f1.w) << 16);
    *(uint4*)(wlds + (size_t)cc * 512 + ln * 8) = pk;
  }

  const float bhr = b_hh[c0 + cl];
  const float bhz = b_hh[512 + c0 + cl];
  const float bhn = b_hh[1024 + c0 + cl];
  float hcur[4] = {0.f, 0.f, 0.f, 0.f};

  // gx for step 0
  ushort_t gxv[3][4];
#pragma unroll
  for (int g = 0; g < 3; ++g)
#pragma unroll
    for (int r = 0; r < 4; ++r)
      gxv[g][r] = gx[(size_t)(0 * 16 + (q << 2) + r) * GU_ + g * 512 + c0 + cl];

  __syncthreads();   // wlds ready; the only barrier in the kernel

  uintx4 sv[16][2];  // in-flight h slices (live across the loop boundary)
  int budget = 1 << 16;   // global retry-round budget: clean FAIL, no hang

  for (int step = 0; step < S_; ++step) {
    f32x4 acc[3] = {{0.f,0.f,0.f,0.f},{0.f,0.f,0.f,0.f},{0.f,0.f,0.f,0.f}};

    if (step > 0) {
      const uint_t want = (uint_t)step;           // producers tagged h(step-1) with step
      const uint_t wantw = want | (want << 16);
      const uint_t* dbase = mdata + (size_t)((step - 1) & 1) * 8192 +
                            l16 * 512 + q * 8;
      // ---- round 1: wait for the tail-issued reads (+ y/gx drains) ----
      asm volatile("s_waitcnt vmcnt(0)" ::: "memory");
      __builtin_amdgcn_sched_barrier(0);
      uint_t stale = 0xFFFFu;
#pragma unroll
      for (int ks = 0; ks < 16; ++ks) {
        uint_t bad = vbad(sv[ks][0], sv[ks][1], wantw);
        if (__all(bad == 0)) stale &= ~(1u << ks);
      }
      // ---- parallel retry rounds: reissue ALL stale slices per round ----
      while (stale != 0 && --budget >= 0) {
#pragma unroll
        for (int ks = 0; ks < 16; ++ks)
          if (stale & (1u << ks))
            asm volatile("global_load_dwordx4 %0, %2, off sc0 sc1\n\t"
                         "global_load_dwordx4 %1, %2, off offset:16 sc0 sc1"
                         : "=&v"(sv[ks][0]), "=&v"(sv[ks][1])
                         : "v"(dbase + ks * 32) : "memory");
        asm volatile("s_waitcnt vmcnt(0)" ::: "memory");
        __builtin_amdgcn_sched_barrier(0);
#pragma unroll
        for (int ks = 0; ks < 16; ++ks)
          if (stale & (1u << ks)) {
            uint_t bad = vbad(sv[ks][0], sv[ks][1], wantw);
            if (__all(bad == 0)) stale &= ~(1u << ks);
          }
      }
      // ---- MFMA: 16 slices x 3 gates (weights from LDS) ----
#pragma unroll
      for (int ks = 0; ks < 16; ++ks) {
        union { bf16x8 h8; uint_t u[4]; } hu;
        hu.u[0] = __builtin_amdgcn_perm(sv[ks][0][1], sv[ks][0][0], 0x05040100u);
        hu.u[1] = __builtin_amdgcn_perm(sv[ks][0][3], sv[ks][0][2], 0x05040100u);
        hu.u[2] = __builtin_amdgcn_perm(sv[ks][1][1], sv[ks][1][0], 0x05040100u);
        hu.u[3] = __builtin_amdgcn_perm(sv[ks][1][3], sv[ks][1][2], 0x05040100u);
#pragma unroll
        for (int gi = 0; gi < 3; ++gi) {
          bf16x8 wf = *(const bf16x8*)(wlds +
              (size_t)(((gi * 2 + wv) * 16) + ks) * 512 + lane * 8);
          acc[gi] = __builtin_amdgcn_mfma_f32_16x16x32_bf16(hu.h8, wf, acc[gi], 0, 0, 0);
        }
      }
    }

    // ---- gates (row=batch=q*4+r, col=c0+cl) ----
    ushort_t hb16[4];
#pragma unroll
    for (int r = 0; r < 4; ++r) {
      float xr  = bf2f(gxv[0][r]);
      float xz  = bf2f(gxv[1][r]);
      float xnn = bf2f(gxv[2][r]);
      float rr = 1.f / (1.f + __expf(-(xr + acc[0][r] + bhr)));
      float zz = 1.f / (1.f + __expf(-(xz + acc[1][r] + bhz)));
      float na = xnn + rr * (acc[2][r] + bhn);
      float ng = 1.f - 2.f / (1.f + __expf(2.f * na));   // tanh, inf-safe
      float hv = (1.f - zz) * ng + zz * hcur[r];
      hcur[r] = hv;
      hb16[r] = f2bf(hv);
    }

    // ---- publish self-tagged dwords + IMMEDIATELY issue next-step reads
    //      (they cross the fabric while other producers commit) ----
    if (step < S_ - 1) {
      const int oslot = step & 1;
      const uint_t tag = ((uint_t)(step + 1)) << 16;
      uint_t* pb = mdata + (size_t)oslot * 8192 + (c0 + cl);
#pragma unroll
      for (int r = 0; r < 4; ++r) {
        uint_t dw = (uint_t)hb16[r] | tag;
        asm volatile("global_store_dword %0, %1, off sc0 sc1"
                     :: "v"(pb + ((q << 2) + r) * 512), "v"(dw) : "memory");
      }
      const uint_t* ndbase = mdata + (size_t)oslot * 8192 + l16 * 512 + q * 8;
#pragma unroll
      for (int ks = 0; ks < 16; ++ks)
        asm volatile("global_load_dwordx4 %0, %2, off sc0 sc1\n\t"
                     "global_load_dwordx4 %1, %2, off offset:16 sc0 sc1"
                     : "=&v"(sv[ks][0]), "=&v"(sv[ks][1])
                     : "v"(ndbase + ks * 32) : "memory");
    }

    // ---- y stores ([s*16+b][512]; drain under next head vmcnt(0)) ----
#pragma unroll
    for (int r = 0; r < 4; ++r)
      y[(size_t)(step * 16 + (q << 2) + r) * U_ + c0 + cl] = hb16[r];

    // ---- gx prefetch for step+1 (drains under next head vmcnt(0)) ----
    if (step + 1 < S_) {
#pragma unroll
      for (int g = 0; g < 3; ++g)
#pragma unroll
        for (int r = 0; r < 4; ++r)
          gxv[g][r] = gx[(size_t)((step + 1) * 16 + (q << 2) + r) * GU_ +
                         g * 512 + c0 + cl];
    }
  }

#pragma unroll
  for (int r = 0; r < 4; ++r)
    h_last[((q << 2) + r) * 512 + c0 + cl] = hcur[r];
}

extern "C" void kernel_launch(void* const* d_in, const int* in_sizes, int n_in,
                              void* d_out, int out_size, void* d_ws, size_t ws_size,
                              hipStream_t stream) {
  const float* x     = (const float*)d_in[0];
  const float* ln_g  = (const float*)d_in[1];
  const float* ln_b  = (const float*)d_in[2];
  const float* w_in  = (const float*)d_in[3];
  const float* b_in  = (const float*)d_in[4];
  const float* w_ih  = (const float*)d_in[5];
  const float* w_hh  = (const float*)d_in[6];
  const float* b_ih  = (const float*)d_in[7];
  const float* b_hh  = (const float*)d_in[8];
  const float* w_out = (const float*)d_in[9];
  const float* b_out = (const float*)d_in[10];

  float* out = (float*)d_out;                       // [B,S,D] fp32
  float* h_last = out + (size_t)B_ * S_ * D_;       // [B,U] fp32

  char* ws = (char*)d_ws;
  size_t off = 0;
  ushort_t* xn   = (ushort_t*)(ws + off); off += (size_t)B_ * S_ * D_ * 2;   // 32 MB
  ushort_t* u    = (ushort_t*)(ws + off); off += (size_t)B_ * S_ * U_ * 2;   // 16 MB
  ushort_t* gx   = (ushort_t*)(ws + off); off += (size_t)B_ * S_ * GU_ * 2;  // 48 MB, [s*16+b][1536]
  ushort_t* y    = (ushort_t*)(ws + off); off += (size_t)B_ * S_ * U_ * 2;   // 16 MB, [s*16+b][512]
  ushort_t* winb = (ushort_t*)(ws + off); off += (size_t)U_ * D_ * 2;
  ushort_t* wihb = (ushort_t*)(ws + off); off += (size_t)GU_ * U_ * 2;
  ushort_t* woub = (ushort_t*)(ws + off); off += (size_t)D_ * U_ * 2;
  // data mailbox: 2 slots x 16 batches x 512 cols x 4B dwords = 64 KB,
  // aliasing the dead xn buffer (xn's last use is GEMM1, stream-ordered
  // before the memset and scan). Zeroed below: tag field 0 matches no want
  // (wants are 1..1023).
  uint_t* mdata  = (uint_t*)xn;

  cvt_f32_bf16<<<512, 256, 0, stream>>>((const float4*)w_in,  (ushort4*)winb, U_ * D_ / 4);
  cvt_f32_bf16<<<512, 256, 0, stream>>>((const float4*)w_ih,  (ushort4*)wihb, GU_ * U_ / 4);
  cvt_f32_bf16<<<512, 256, 0, stream>>>((const float4*)w_out, (ushort4*)woub, D_ * U_ / 4);

  ln_kernel<<<B_ * S_, 256, 0, stream>>>(x, ln_g, ln_b, xn);

  // u = xn @ w_in^T + b_in  (M=16384, N=512, K=1024)
  gemm_bt<0, 1, 0, 0><<<dim3(B_ * S_ / 128, U_ / 128), 256, 0, stream>>>(
      xn, winb, b_in, nullptr, u, B_ * S_, U_, D_);
  // gx = u @ w_ih^T + b_ih  (M=16384, N=1536, K=512), C rows -> [s*16+b]
  gemm_bt<0, 1, 0, 1><<<dim3(B_ * S_ / 128, GU_ / 128), 256, 0, stream>>>(
      u, wihb, b_ih, nullptr, gx, B_ * S_, GU_, U_);

  // zero the mailbox (stream-ordered after GEMM1's last read of xn)
  hipMemsetAsync(mdata, 0, 65536, stream);

  // sequential GRU: 16 wgs x 128 threads, 96 KB dynamic LDS (all w_hh)
  (void)hipFuncSetAttribute(reinterpret_cast<const void*>(scan_kernel),
                            hipFuncAttributeMaxDynamicSharedMemorySize, 98304);
  scan_kernel<<<16, 128, 98304, stream>>>(gx, w_hh, b_hh, mdata, y, h_last);

  // out = x + y @ w_out^T + b_out  (M=16384, N=1024, K=512), A rows [s*16+b]
  gemm_bt<1, 0, 1, 0><<<dim3(B_ * S_ / 128, D_ / 128), 256, 0, stream>>>(
      y, woub, b_out, x, out, B_ * S_, D_, U_);
}

// Round 9
// 3071.714 us; speedup vs baseline: 1.9001x; 1.9001x over previous
//
#include <hip/hip_runtime.h>

typedef unsigned short ushort_t;
typedef unsigned int uint_t;
typedef __attribute__((ext_vector_type(8))) short bf16x8;
typedef __attribute__((ext_vector_type(4))) float f32x4;
typedef __attribute__((ext_vector_type(4))) unsigned int uintx4;

#define B_  16
#define S_  1024
#define D_  1024
#define U_  512
#define GU_ 1536  // 3*U

// ---------- bf16 helpers (RNE) ----------
__device__ __forceinline__ ushort_t f2bf(float f) {
  union { float f; uint_t u; } v; v.f = f;
  uint_t r = v.u + 0x7fffu + ((v.u >> 16) & 1u);
  return (ushort_t)(r >> 16);
}
__device__ __forceinline__ float bf2f(ushort_t b) {
  union { uint_t u; float f; } v; v.u = ((uint_t)b) << 16; return v.f;
}

// ---------- fp32 -> bf16 weight conversion ----------
__global__ void cvt_f32_bf16(const float4* __restrict__ in, ushort4* __restrict__ out, int n4) {
  int i = blockIdx.x * blockDim.x + threadIdx.x;
  int stride = gridDim.x * blockDim.x;
  for (; i < n4; i += stride) {
    float4 f = in[i];
    ushort4 o; o.x = f2bf(f.x); o.y = f2bf(f.y); o.z = f2bf(f.z); o.w = f2bf(f.w);
    out[i] = o;
  }
}

// ---------- LayerNorm: x fp32 [BS, 1024] -> xn bf16 ----------
__global__ __launch_bounds__(256) void ln_kernel(
    const float* __restrict__ x, const float* __restrict__ gamma,
    const float* __restrict__ beta, ushort_t* __restrict__ xn)
{
  int row = blockIdx.x;
  int t = threadIdx.x;
  const float* xr = x + (size_t)row * 1024;
  float4 v = *(const float4*)(xr + t * 4);
  float s = v.x + v.y + v.z + v.w;
  float ss = v.x * v.x + v.y * v.y + v.z * v.z + v.w * v.w;
#pragma unroll
  for (int o = 32; o > 0; o >>= 1) {
    s  += __shfl_down(s, o, 64);
    ss += __shfl_down(ss, o, 64);
  }
  __shared__ float red[2][4];
  __shared__ float mv[2];
  int wv = t >> 6, ln = t & 63;
  if (ln == 0) { red[0][wv] = s; red[1][wv] = ss; }
  __syncthreads();
  if (t == 0) {
    float S1 = red[0][0] + red[0][1] + red[0][2] + red[0][3];
    float S2 = red[1][0] + red[1][1] + red[1][2] + red[1][3];
    float mu = S1 * (1.f / 1024.f);
    float var = S2 * (1.f / 1024.f) - mu * mu;
    mv[0] = mu;
    mv[1] = rsqrtf(var + 1e-5f);
  }
  __syncthreads();
  float mu = mv[0], rs = mv[1];
  float4 gm = *(const float4*)(gamma + t * 4);
  float4 bt = *(const float4*)(beta + t * 4);
  ushort4 o;
  o.x = f2bf((v.x - mu) * rs * gm.x + bt.x);
  o.y = f2bf((v.y - mu) * rs * gm.y + bt.y);
  o.z = f2bf((v.z - mu) * rs * gm.z + bt.z);
  o.w = f2bf((v.w - mu) * rs * gm.w + bt.w);
  *(ushort4*)(xn + (size_t)row * 1024 + t * 4) = o;
}

// ---------- GEMM: C[M,N] = A[M,K](bf16) @ Bw[N,K](bf16)^T + bias (+resid) ----------
template<int RES, int OBF>
__global__ __launch_bounds__(256, 2) void gemm_bt(
    const ushort_t* __restrict__ A, const ushort_t* __restrict__ Bw,
    const float* __restrict__ bias, const float* __restrict__ resid,
    void* __restrict__ Cout, int M, int N, int K)
{
  __shared__ ushort_t As[128][40];
  __shared__ ushort_t Bs[128][40];
  int bm = blockIdx.x, bn = blockIdx.y;
  int tid = threadIdx.x;
  int wave = tid >> 6, lane = tid & 63;
  int wm = wave >> 1, wn = wave & 1;
  int q = lane >> 4, l16 = lane & 15;
  f32x4 acc[4][4];
#pragma unroll
  for (int i = 0; i < 4; i++)
#pragma unroll
    for (int j = 0; j < 4; j++) acc[i][j] = (f32x4){0.f, 0.f, 0.f, 0.f};
  int r0 = tid >> 2, kc = tid & 3;
  const int nk = K >> 5;
  for (int it = 0; it < nk; ++it) {
#pragma unroll
    for (int h = 0; h < 2; ++h) {
      int r = r0 + h * 64;
      const uint4* pa = (const uint4*)(A + (size_t)(bm * 128 + r) * K + it * 32 + kc * 8);
      *(uint4*)&As[r][kc * 8] = *pa;
      const uint4* pb = (const uint4*)(Bw + (size_t)(bn * 128 + r) * K + it * 32 + kc * 8);
      *(uint4*)&Bs[r][kc * 8] = *pb;
    }
    __syncthreads();
    bf16x8 af[4], bfr[4];
#pragma unroll
    for (int i = 0; i < 4; i++) af[i]  = *(bf16x8*)&As[wm * 64 + i * 16 + l16][q * 8];
#pragma unroll
    for (int j = 0; j < 4; j++) bfr[j] = *(bf16x8*)&Bs[wn * 64 + j * 16 + l16][q * 8];
#pragma unroll
    for (int i = 0; i < 4; i++)
#pragma unroll
      for (int j = 0; j < 4; j++)
        acc[i][j] = __builtin_amdgcn_mfma_f32_16x16x32_bf16(af[i], bfr[j], acc[i][j], 0, 0, 0);
    __syncthreads();
  }
#pragma unroll
  for (int i = 0; i < 4; i++) {
#pragma unroll
    for (int j = 0; j < 4; j++) {
      int n = bn * 128 + wn * 64 + j * 16 + l16;
      float bv = bias[n];
#pragma unroll
      for (int rr = 0; rr < 4; rr++) {
        int m = bm * 128 + wm * 64 + i * 16 + q * 4 + rr;
        float v = acc[i][j][rr] + bv;
        if (RES) v += resid[(size_t)m * N + n];
        if (OBF) ((ushort_t*)Cout)[(size_t)m * N + n] = f2bf(v);
        else     ((float*)Cout)[(size_t)m * N + n] = v;
      }
    }
  }
}

// ---------- GRU scan (16 wgs, release-protocol mailbox) ----------
// wg m owns h-cols [32m,32m+32) for all 16 batches. Per step, publish:
//   data stores (2 bf16 cols/dword, sc0 sc1) -> __syncthreads (vmcnt(0) drain
//   for BOTH waves) -> one tag dword mtag[slot][m] = step+1 (sc0 sc1).
// Reader: poll the 64B tag line (1 load/iter) until all 16 == step, then read
// the 16KB data slot exactly ONCE. 2-slot ping-pong safe: a wg's tag for step
// s is its receipt that it finished consuming slot s-1 (publish follows data
// read in program order), and slot parity p is only overwritten at step p+2,
// which requires all 16 tags of step p+1.
//
// Session verdict (R0-R8, 9 measured variants): per-step time == 4 serialized
// device-scope round-trips (release drain, tag commit, discovery, payload
// read) ~= 2.8us. Attempts to remove hops: self-validating dword mailbox
// (serial/advisory/speculative-parallel retries: 5.0/4.6/5.9/5.6ms — cheap-
// poll/expensive-read asymmetry is load-bearing), direct-to-reg data path
// (2.92ms, neutral: data-path work is free), same-XCD + L2-scope (wrong
// results/hang: sc0-only visibility unreliable). This is the 16-wg
// all-to-all communication-latency floor, not a memory/compute roofline.
__global__ __launch_bounds__(128, 1) void scan_kernel(
    const ushort_t* __restrict__ gx, const float* __restrict__ w_hh,
    const float* __restrict__ b_hh, uint_t* __restrict__ mdata,
    uint_t* __restrict__ mtag, ushort_t* __restrict__ y,
    float* __restrict__ h_last)
{
  extern __shared__ char smem[];
  ushort_t* wlds = (ushort_t*)smem;   // 48 KB: [gi*16+wv*8+ks][lane][8] B-frags, ks 0..7
  char* hshb = smem + 49152;          // 16 KB: [b][512] bf16, 16B-chunk XOR-(b&7) swizzle

  const int m = blockIdx.x;
  const int c0 = m * 32;
  const int t = threadIdx.x;
  const int wv = t >> 6, lane = t & 63, q = lane >> 4, l16 = lane & 15;
  const int cl = (wv << 4) + l16;      // owned hcol within slice, 0..31

  // ---- w_hh ks=0..7 fragments into LDS (both waves' col-halves) ----
  for (int idx = t; idx < 48 * 64; idx += 128) {
    int cc = idx >> 6, ln = idx & 63;
    int gi = cc >> 4, wv2 = (cc >> 3) & 1, ks = cc & 7;
    int n = c0 + (wv2 << 4) + (ln & 15);
    int k0 = (ks << 5) + ((ln >> 4) << 3);
    const float* src = w_hh + (size_t)(gi * 512 + n) * 512 + k0;
    float4 f0 = *(const float4*)src;
    float4 f1 = *(const float4*)(src + 4);
    uint4 pk;
    pk.x = (uint_t)f2bf(f0.x) | ((uint_t)f2bf(f0.y) << 16);
    pk.y = (uint_t)f2bf(f0.z) | ((uint_t)f2bf(f0.w) << 16);
    pk.z = (uint_t)f2bf(f1.x) | ((uint_t)f2bf(f1.y) << 16);
    pk.w = (uint_t)f2bf(f1.z) | ((uint_t)f2bf(f1.w) << 16);
    *(uint4*)(wlds + (size_t)cc * 512 + ln * 8) = pk;
  }
  // ---- w_hh ks=8..15 fragments in VGPRs (96 regs) ----
  bf16x8 wreg[3][8];
#pragma unroll
  for (int gi = 0; gi < 3; ++gi)
#pragma unroll
    for (int k8 = 0; k8 < 8; ++k8) {
      const float* src = w_hh + (size_t)(gi * 512 + c0 + cl) * 512 + (8 + k8) * 32 + q * 8;
      float4 f0 = *(const float4*)src;
      float4 f1 = *(const float4*)(src + 4);
      bf16x8 wf;
      wf[0] = (short)f2bf(f0.x); wf[1] = (short)f2bf(f0.y);
      wf[2] = (short)f2bf(f0.z); wf[3] = (short)f2bf(f0.w);
      wf[4] = (short)f2bf(f1.x); wf[5] = (short)f2bf(f1.y);
      wf[6] = (short)f2bf(f1.z); wf[7] = (short)f2bf(f1.w);
      wreg[gi][k8] = wf;
    }

  const float bhr = b_hh[c0 + cl];
  const float bhz = b_hh[512 + c0 + cl];
  const float bhn = b_hh[1024 + c0 + cl];
  float hcur[4] = {0.f, 0.f, 0.f, 0.f};

  // gx for step 0
  ushort_t gxv[3][4];
#pragma unroll
  for (int g = 0; g < 3; ++g)
#pragma unroll
    for (int r = 0; r < 4; ++r)
      gxv[g][r] = gx[(size_t)(((q << 2) + r) * S_) * GU_ + g * 512 + c0 + cl];

  // h_0 = 0
  for (int i = t; i < 4096; i += 128) ((uint_t*)hshb)[i] = 0u;

  const int l64 = t & 63;
  for (int step = 0; step < S_; ++step) {
    if (step > 0) {
      const uint_t want = (uint_t)step;       // publishers of step-1 wrote tag step
      const int slot = (step - 1) & 1;
      // ---- poll the 16-tag line (one dword per lane, broadcast line) ----
      const uint_t* tp = mtag + slot * 16 + (lane & 15);
      uint_t tv;
      do {
        asm volatile("global_load_dword %0, %1, off sc0 sc1"
                     : "=v"(tv) : "v"(tp) : "memory");
        asm volatile("s_waitcnt vmcnt(0)" ::: "memory");
      } while (!__all((int)(tv == want)));
      // ---- single data read: 8 x dwordx4 per thread covers the 16 KB slot ----
      const uint_t* db = mdata + slot * 4096;
      uintx4 vals[8];
#pragma unroll
      for (int j = 0; j < 8; ++j) {
        const uint_t* p = db + j * 512 + t * 4;
        asm volatile("global_load_dwordx4 %0, %1, off sc0 sc1"
                     : "=v"(vals[j]) : "v"(p) : "memory");
      }
      asm volatile("s_waitcnt vmcnt(0)" ::: "memory");
      // ---- stage: thread t burst j = batch 2j+wv, cols [8*l64, 8*l64+8) ----
#pragma unroll
      for (int j = 0; j < 8; ++j) {
        int b = 2 * j + wv;
        *(uint4*)(hshb + b * 1024 + ((l64 ^ (b & 7)) << 4)) = *(uint4*)&vals[j];
      }
    }
    __syncthreads();

    // ---- MFMA: gh tiles (rows=batch, cols=this wave's 16 hcols x 3 gates) ----
    f32x4 acc[3] = {{0.f,0.f,0.f,0.f},{0.f,0.f,0.f,0.f},{0.f,0.f,0.f,0.f}};
#pragma unroll
    for (int ks = 0; ks < 16; ++ks) {
      bf16x8 hf = *(bf16x8*)(hshb + l16 * 1024 +
                             ((((ks << 2) + q) ^ (l16 & 7)) << 4));
#pragma unroll
      for (int gi = 0; gi < 3; ++gi) {
        bf16x8 wf;
        if (ks < 8) wf = *(bf16x8*)(wlds + (size_t)((gi * 2 + wv) * 8 + ks) * 512 + lane * 8);
        else        wf = wreg[gi][ks - 8];
        acc[gi] = __builtin_amdgcn_mfma_f32_16x16x32_bf16(hf, wf, acc[gi], 0, 0, 0);
      }
    }

    // ---- gates (row=batch=q*4+r, col=c0+cl) ----
    ushort_t hb16[4];
#pragma unroll
    for (int r = 0; r < 4; ++r) {
      float xr  = bf2f(gxv[0][r]);
      float xz  = bf2f(gxv[1][r]);
      float xnn = bf2f(gxv[2][r]);
      float rr = 1.f / (1.f + __expf(-(xr + acc[0][r] + bhr)));
      float zz = 1.f / (1.f + __expf(-(xz + acc[1][r] + bhz)));
      float na = xnn + rr * (acc[2][r] + bhn);
      float ng = 1.f - 2.f / (1.f + __expf(2.f * na));   // tanh, inf-safe
      float hv = (1.f - zz) * ng + zz * hcur[r];
      hcur[r] = hv;
      hb16[r] = f2bf(hv);
    }

    // ---- publish (skip at last step: nobody polls it) ----
    if (step < S_ - 1) {
      const int oslot = step & 1;
#pragma unroll
      for (int r = 0; r < 4; ++r) {
        uint_t other = (uint_t)__shfl_xor((int)(uint_t)hb16[r], 1, 64);
        if ((lane & 1) == 0) {
          uint_t dw = ((uint_t)hb16[r]) | (other << 16);   // even col lo, odd hi
          int b = (q << 2) + r;
          uint_t* pp = mdata + oslot * 4096 + b * 256 + ((c0 + cl) >> 1);
          asm volatile("global_store_dword %0, %1, off sc0 sc1"
                       :: "v"(pp), "v"(dw) : "memory");
        }
      }
      __syncthreads();   // built-in vmcnt(0): BOTH waves' data stores drained
      if (t == 0) {
        uint_t tagv = (uint_t)(step + 1);
        uint_t* tp = mtag + oslot * 16 + m;
        asm volatile("global_store_dword %0, %1, off sc0 sc1"
                     :: "v"(tp), "v"(tagv) : "memory");
      }
    }

    // ---- y stores (plain cached; drained at kernel end) ----
#pragma unroll
    for (int r = 0; r < 4; ++r)
      y[((size_t)((q << 2) + r) * S_ + step) * U_ + c0 + cl] = hb16[r];

    // ---- gx prefetch for next step (in flight across the next poll) ----
    if (step + 1 < S_) {
#pragma unroll
      for (int g = 0; g < 3; ++g)
#pragma unroll
        for (int r = 0; r < 4; ++r)
          gxv[g][r] = gx[((size_t)((q << 2) + r) * S_ + step + 1) * GU_ +
                         g * 512 + c0 + cl];
    }
  }

#pragma unroll
  for (int r = 0; r < 4; ++r)
    h_last[((q << 2) + r) * 512 + c0 + cl] = hcur[r];
}

extern "C" void kernel_launch(void* const* d_in, const int* in_sizes, int n_in,
                              void* d_out, int out_size, void* d_ws, size_t ws_size,
                              hipStream_t stream) {
  const float* x     = (const float*)d_in[0];
  const float* ln_g  = (const float*)d_in[1];
  const float* ln_b  = (const float*)d_in[2];
  const float* w_in  = (const float*)d_in[3];
  const float* b_in  = (const float*)d_in[4];
  const float* w_ih  = (const float*)d_in[5];
  const float* w_hh  = (const float*)d_in[6];
  const float* b_ih  = (const float*)d_in[7];
  const float* b_hh  = (const float*)d_in[8];
  const float* w_out = (const float*)d_in[9];
  const float* b_out = (const float*)d_in[10];

  float* out = (float*)d_out;                       // [B,S,D] fp32
  float* h_last = out + (size_t)B_ * S_ * D_;       // [B,U] fp32

  char* ws = (char*)d_ws;
  size_t off = 0;
  ushort_t* xn   = (ushort_t*)(ws + off); off += (size_t)B_ * S_ * D_ * 2;   // 32 MB
  ushort_t* u    = (ushort_t*)(ws + off); off += (size_t)B_ * S_ * U_ * 2;   // 16 MB
  ushort_t* gx   = (ushort_t*)(ws + off); off += (size_t)B_ * S_ * GU_ * 2;  // 48 MB
  ushort_t* y    = (ushort_t*)(ws + off); off += (size_t)B_ * S_ * U_ * 2;   // 16 MB
  ushort_t* winb = (ushort_t*)(ws + off); off += (size_t)U_ * D_ * 2;
  ushort_t* wihb = (ushort_t*)(ws + off); off += (size_t)GU_ * U_ * 2;
  ushort_t* woub = (ushort_t*)(ws + off); off += (size_t)D_ * U_ * 2;
  uint_t* mtag   = (uint_t*)(ws + off);   off += 256;          // 2 slots x 16 tags
  // data mailbox (2 slots x 16 KB) aliases the dead xn buffer: xn's last use
  // is GEMM1 (stream-ordered before the scan); data is only read after a tag
  // validates, and tags live in fresh ws (poison 0xAAAAAAAA can't forge 1..1024).
  uint_t* mdata  = (uint_t*)xn;

  cvt_f32_bf16<<<512, 256, 0, stream>>>((const float4*)w_in,  (ushort4*)winb, U_ * D_ / 4);
  cvt_f32_bf16<<<512, 256, 0, stream>>>((const float4*)w_ih,  (ushort4*)wihb, GU_ * U_ / 4);
  cvt_f32_bf16<<<512, 256, 0, stream>>>((const float4*)w_out, (ushort4*)woub, D_ * U_ / 4);

  ln_kernel<<<B_ * S_, 256, 0, stream>>>(x, ln_g, ln_b, xn);

  // u = xn @ w_in^T + b_in  (M=16384, N=512, K=1024)
  gemm_bt<0, 1><<<dim3(B_ * S_ / 128, U_ / 128), 256, 0, stream>>>(
      xn, winb, b_in, nullptr, u, B_ * S_, U_, D_);
  // gx = u @ w_ih^T + b_ih  (M=16384, N=1536, K=512)
  gemm_bt<0, 1><<<dim3(B_ * S_ / 128, GU_ / 128), 256, 0, stream>>>(
      u, wihb, b_ih, nullptr, gx, B_ * S_, GU_, U_);

  // belt-and-braces: zero the tag lines (0 and 0xAAAAAAAA are both non-tags)
  hipMemsetAsync(mtag, 0, 256, stream);

  // sequential GRU: 16 wgs x 128 threads, 64 KB pure-dynamic LDS (R2-proven)
  (void)hipFuncSetAttribute(reinterpret_cast<const void*>(scan_kernel),
                            hipFuncAttributeMaxDynamicSharedMemorySize, 65536);
  scan_kernel<<<16, 128, 65536, stream>>>(gx, w_hh, b_hh, mdata, mtag, y, h_last);

  // out = x + y @ w_out^T + b_out  (M=16384, N=1024, K=512)
  gemm_bt<1, 0><<<dim3(B_ * S_ / 128, D_ / 128), 256, 0, stream>>>(
      y, woub, b_out, x, out, B_ * S_, D_, U_);
}